// Round 9
// baseline (455.882 us; speedup 1.0000x reference)
//
#include <hip/hip_runtime.h>
#include <math.h>

// Problem constants
#define BB 8
#define MM 128
#define NNN 128
#define II 64
#define OO 64
#define KMODES 32
#define HHID 256

#define NH (BB*II*MM*NNN)   // 8388608 elements of s / out

// ---------------------------------------------------------------------------
// Kernel 1: fused setup.
// Blocks 0..31: interleaved DFT trig table Tp[64][128]:
//   rows 0..31 :  cos(2*pi*k*n/128)/sqrt(128)
//   rows 32..63: -sin(2*pi*k*n/128)/sqrt(128)
// Blocks 32..1055: repack fw1 (I,O,MODES,2) -> fwp1 (MODES,I,O,2)
// Blocks 1056..2079: repack fw2 likewise.
// ---------------------------------------------------------------------------
__global__ __launch_bounds__(256) void k_setup(const float* __restrict__ fw1,
                                               const float* __restrict__ fw2,
                                               float* __restrict__ Tp,
                                               float* __restrict__ fwp1,
                                               float* __restrict__ fwp2) {
    int blk = blockIdx.x;
    if (blk < 32) {
        int t = blk * 256 + threadIdx.x;      // t < 8192
        int kp = t >> 7, n = t & 127, k = kp & 31;
        float ang = (float)((k * n) & 127) * 0.049087385212340516f; // 2*pi/128
        float sv, cv;
        sincosf(ang, &sv, &cv);
        const float rs = 0.08838834764831845f; // 1/sqrt(128)
        Tp[t] = (kp < 32 ? cv : -sv) * rs;
    } else {
        int r = blk - 32;
        const float* fw = (r < 1024) ? fw1 : fw2;
        float* fwp      = (r < 1024) ? fwp1 : fwp2;
        int t = (r & 1023) * 256 + threadIdx.x;   // t < 262144
        int c = t & 1;
        int o = (t >> 1) & 63;
        int i = (t >> 7) & 63;
        int k = t >> 13;
        fwp[t] = fw[((i * 64 + o) * 32 + k) * 2 + c];
    }
}

// ---------------------------------------------------------------------------
// Kernel 2: fused spectral conv for one line, register-tiled.
// Builds its 64x128 input line directly from x+z (no h/hT intermediates).
// DIR=0: block (b,m): hrow[i][n] = (x+z)[b][m][n][i]; DFT over n, mix fwp1,
//        iDFT over n, s[b][m][n][o] = acc
// DIR=1: block (b,n): hrow[i][m] = (x+z)[b][m][n][i]; DFT over m, mix fwp2,
//        iDFT over m, s[b][m][n][o] += acc
// LDS: hrow[64][132] / overlay oy[2][32][68]; fr/fi[32][65]. 50432 B -> 3/CU.
// ---------------------------------------------------------------------------
template <int DIR>
__global__ __launch_bounds__(256) void k_spec(const float* __restrict__ x,
                                              const float* __restrict__ z,
                                              const float* __restrict__ fwp,
                                              const float* __restrict__ Tp,
                                              float* s) {
    int b = blockIdx.x >> 7, line = blockIdx.x & 127;
    __shared__ float lds[12608];
    float* hrow = lds;                    // [64][132]
    float* fr   = lds + 64 * 132;         // [32][65]
    float* fi   = fr + 32 * 65;           // [32][65]
    float* oyr  = lds;                    // overlay [32][68]
    float* oyi  = lds + 32 * 68;          // overlay [32][68]
    const int t = threadIdx.x;

    // ---- fused load: build hrow[i][line-dim] from x+z
    if (DIR == 0) {
        // x[b][line][n][i] contiguous 8192-float slab
        const float* xb = x + (size_t)(b * 128 + line) * 8192;
        const float* zb = z + (size_t)(b * 128 + line) * 8192;
        for (int q = t; q < 2048; q += 256) {
            int n = q >> 4, i4 = (q & 15) * 4;
            float4 xv = *(const float4*)(xb + n * 64 + i4);
            float4 zv = *(const float4*)(zb + n * 64 + i4);
            hrow[(i4 + 0) * 132 + n] = xv.x + zv.x;
            hrow[(i4 + 1) * 132 + n] = xv.y + zv.y;
            hrow[(i4 + 2) * 132 + n] = xv.z + zv.z;
            hrow[(i4 + 3) * 132 + n] = xv.w + zv.w;
        }
    } else {
        // per m: 256B chunk x[b][m][line][:]
        for (int q = t; q < 2048; q += 256) {
            int m = q >> 4, i4 = (q & 15) * 4;
            size_t off = ((size_t)(b * 128 + m) * 128 + line) * 64 + i4;
            float4 xv = *(const float4*)(x + off);
            float4 zv = *(const float4*)(z + off);
            hrow[(i4 + 0) * 132 + m] = xv.x + zv.x;
            hrow[(i4 + 1) * 132 + m] = xv.y + zv.y;
            hrow[(i4 + 2) * 132 + m] = xv.z + zv.z;
            hrow[(i4 + 3) * 132 + m] = xv.w + zv.w;
        }
    }
    __syncthreads();

    // ---- DFT: C'[k'][i] = sum_n Tp[k'][n] * hrow[i][n]; k'<32 -> fr, else fi
    {
        int ti = t & 15, tk = t >> 4;          // ti: i base, tk: k' base
        float acc[4][4];
        #pragma unroll
        for (int c = 0; c < 4; ++c)
            #pragma unroll
            for (int d = 0; d < 4; ++d) acc[c][d] = 0.f;
        for (int ng = 0; ng < 32; ++ng) {
            float4 Tv[4], Hv[4];
            #pragma unroll
            for (int c = 0; c < 4; ++c)
                Tv[c] = *(const float4*)(Tp + (tk + 16 * c) * 128 + 4 * ng);
            #pragma unroll
            for (int d = 0; d < 4; ++d)
                Hv[d] = *(const float4*)(hrow + (ti + 16 * d) * 132 + 4 * ng);
            #pragma unroll
            for (int c = 0; c < 4; ++c)
                #pragma unroll
                for (int d = 0; d < 4; ++d) {
                    acc[c][d] = fmaf(Tv[c].x, Hv[d].x, acc[c][d]);
                    acc[c][d] = fmaf(Tv[c].y, Hv[d].y, acc[c][d]);
                    acc[c][d] = fmaf(Tv[c].z, Hv[d].z, acc[c][d]);
                    acc[c][d] = fmaf(Tv[c].w, Hv[d].w, acc[c][d]);
                }
        }
        __syncthreads();   // all hrow reads done before oy overlay is written
        #pragma unroll
        for (int c = 0; c < 4; ++c)
            #pragma unroll
            for (int d = 0; d < 4; ++d) {
                int i = ti + 16 * d;
                if (c < 2) fr[(tk + 16 * c) * 65 + i] = acc[c][d];
                else       fi[(tk + 16 * (c - 2)) * 65 + i] = acc[c][d];
            }
    }
    __syncthreads();

    // ---- mix: oy[k][o] = wk * sum_i (fr,fi)[k][i] * W[k][i][o]  (complex)
    {
        int k = t >> 3, to = t & 7, o0 = to * 8;
        float accr[8], acci[8];
        #pragma unroll
        for (int u = 0; u < 8; ++u) { accr[u] = 0.f; acci[u] = 0.f; }
        const float4* W4 = (const float4*)(fwp + (size_t)k * 8192 + o0 * 2);
        for (int i = 0; i < 64; ++i) {
            float xr = fr[k * 65 + i], xi = fi[k * 65 + i];
            const float4* Wr = W4 + i * 32;
            float4 wA = Wr[0], wB = Wr[1], wC = Wr[2], wD = Wr[3];
            accr[0] = fmaf(xr, wA.x, fmaf(-xi, wA.y, accr[0]));
            acci[0] = fmaf(xr, wA.y, fmaf( xi, wA.x, acci[0]));
            accr[1] = fmaf(xr, wA.z, fmaf(-xi, wA.w, accr[1]));
            acci[1] = fmaf(xr, wA.w, fmaf( xi, wA.z, acci[1]));
            accr[2] = fmaf(xr, wB.x, fmaf(-xi, wB.y, accr[2]));
            acci[2] = fmaf(xr, wB.y, fmaf( xi, wB.x, acci[2]));
            accr[3] = fmaf(xr, wB.z, fmaf(-xi, wB.w, accr[3]));
            acci[3] = fmaf(xr, wB.w, fmaf( xi, wB.z, acci[3]));
            accr[4] = fmaf(xr, wC.x, fmaf(-xi, wC.y, accr[4]));
            acci[4] = fmaf(xr, wC.y, fmaf( xi, wC.x, acci[4]));
            accr[5] = fmaf(xr, wC.z, fmaf(-xi, wC.w, accr[5]));
            acci[5] = fmaf(xr, wC.w, fmaf( xi, wC.z, acci[5]));
            accr[6] = fmaf(xr, wD.x, fmaf(-xi, wD.y, accr[6]));
            acci[6] = fmaf(xr, wD.y, fmaf( xi, wD.x, acci[6]));
            accr[7] = fmaf(xr, wD.z, fmaf(-xi, wD.w, accr[7]));
            acci[7] = fmaf(xr, wD.w, fmaf( xi, wD.z, acci[7]));
        }
        __syncthreads();   // all fr/fi reads done before oy (hrow overlay) write
        float wk = (k == 0) ? 1.f : 2.f;   // irfft hermitian doubling
        float4 v;
        v.x = wk * accr[0]; v.y = wk * accr[1]; v.z = wk * accr[2]; v.w = wk * accr[3];
        *(float4*)(oyr + k * 68 + o0) = v;
        v.x = wk * accr[4]; v.y = wk * accr[5]; v.z = wk * accr[6]; v.w = wk * accr[7];
        *(float4*)(oyr + k * 68 + o0 + 4) = v;
        v.x = wk * acci[0]; v.y = wk * acci[1]; v.z = wk * acci[2]; v.w = wk * acci[3];
        *(float4*)(oyi + k * 68 + o0) = v;
        v.x = wk * acci[4]; v.y = wk * acci[5]; v.z = wk * acci[6]; v.w = wk * acci[7];
        *(float4*)(oyi + k * 68 + o0 + 4) = v;
    }
    __syncthreads();

    // ---- iDFT + store: s[n2][o] = sum_k oyr[k][o]*Tc[k][n2] + oyi[k][o]*Ts[k][n2]
    {
        int to = t & 7, o0 = to * 8, tn = t >> 3;   // tn 0..31
        float acc[4][8];
        #pragma unroll
        for (int c = 0; c < 4; ++c)
            #pragma unroll
            for (int u = 0; u < 8; ++u) acc[c][u] = 0.f;
        for (int k = 0; k < 32; ++k) {
            float4 r0 = *(const float4*)(oyr + k * 68 + o0);
            float4 r1 = *(const float4*)(oyr + k * 68 + o0 + 4);
            float4 i0 = *(const float4*)(oyi + k * 68 + o0);
            float4 i1 = *(const float4*)(oyi + k * 68 + o0 + 4);
            #pragma unroll
            for (int c = 0; c < 4; ++c) {
                float tc = Tp[k * 128 + tn + 32 * c];
                float ts = Tp[(k + 32) * 128 + tn + 32 * c];
                acc[c][0] = fmaf(r0.x, tc, fmaf(i0.x, ts, acc[c][0]));
                acc[c][1] = fmaf(r0.y, tc, fmaf(i0.y, ts, acc[c][1]));
                acc[c][2] = fmaf(r0.z, tc, fmaf(i0.z, ts, acc[c][2]));
                acc[c][3] = fmaf(r0.w, tc, fmaf(i0.w, ts, acc[c][3]));
                acc[c][4] = fmaf(r1.x, tc, fmaf(i1.x, ts, acc[c][4]));
                acc[c][5] = fmaf(r1.y, tc, fmaf(i1.y, ts, acc[c][5]));
                acc[c][6] = fmaf(r1.z, tc, fmaf(i1.z, ts, acc[c][6]));
                acc[c][7] = fmaf(r1.w, tc, fmaf(i1.w, ts, acc[c][7]));
            }
        }
        #pragma unroll
        for (int c = 0; c < 4; ++c) {
            int n2 = tn + 32 * c;
            size_t idx = (DIR == 0)
                ? ((size_t)((b * 128 + line) * 128 + n2)) * 64 + o0
                : ((size_t)((b * 128 + n2) * 128 + line)) * 64 + o0;
            float4 v0, v1;
            v0.x = acc[c][0]; v0.y = acc[c][1]; v0.z = acc[c][2]; v0.w = acc[c][3];
            v1.x = acc[c][4]; v1.y = acc[c][5]; v1.z = acc[c][6]; v1.w = acc[c][7];
            if (DIR == 0) {
                *(float4*)(s + idx)     = v0;
                *(float4*)(s + idx + 4) = v1;
            } else {
                float4 a0 = *(const float4*)(s + idx);
                float4 a1 = *(const float4*)(s + idx + 4);
                v0.x += a0.x; v0.y += a0.y; v0.z += a0.z; v0.w += a0.w;
                v1.x += a1.x; v1.y += a1.y; v1.z += a1.z; v1.w += a1.w;
                *(float4*)(s + idx)     = v0;
                *(float4*)(s + idx + 4) = v1;
            }
        }
    }
}

// ---------------------------------------------------------------------------
// Kernel 3: FFN + residual, 32 points per block, register-tiled.
// out[p][i] = z[p][i] + relu(s[p]@w1 + b1)@w2 + b2
// s aliases out (both d_out) — block reads its range into LDS, barrier, then
// writes the identical range only.
// ---------------------------------------------------------------------------
__global__ __launch_bounds__(256) void k_ffn(const float* s,
                                             const float* __restrict__ z,
                                             const float* __restrict__ w1,
                                             const float* __restrict__ b1,
                                             const float* __restrict__ w2,
                                             const float* __restrict__ b2,
                                             float* out) {
    int p0 = blockIdx.x * 32;
    __shared__ float st[32 * 64];    // 8 KB
    __shared__ float ht[32 * 256];   // 32 KB
    const int t = threadIdx.x;
    for (int q = t; q < 512; q += 256)
        *(float4*)(st + 4 * q) = *(const float4*)(s + (size_t)p0 * 64 + 4 * q);
    __syncthreads();

    // GEMM1: hidden[p][j] = relu(b1[j] + sum_i st[p][i]*w1[i][j])
    // tile: 4 j (tj+64c) x 8 p (tp*8+dp)
    {
        int tj = t & 63, tp = t >> 6;
        float acc[4][8];
        #pragma unroll
        for (int c = 0; c < 4; ++c) {
            float bj = b1[tj + 64 * c];
            #pragma unroll
            for (int dp = 0; dp < 8; ++dp) acc[c][dp] = bj;
        }
        for (int ig = 0; ig < 16; ++ig) {
            float4 sv[8];
            #pragma unroll
            for (int dp = 0; dp < 8; ++dp)
                sv[dp] = *(const float4*)(st + (tp * 8 + dp) * 64 + 4 * ig);
            float wv[4][4];
            #pragma unroll
            for (int u = 0; u < 4; ++u)
                #pragma unroll
                for (int c = 0; c < 4; ++c)
                    wv[u][c] = w1[(4 * ig + u) * 256 + tj + 64 * c];
            #pragma unroll
            for (int c = 0; c < 4; ++c)
                #pragma unroll
                for (int dp = 0; dp < 8; ++dp) {
                    acc[c][dp] = fmaf(sv[dp].x, wv[0][c], acc[c][dp]);
                    acc[c][dp] = fmaf(sv[dp].y, wv[1][c], acc[c][dp]);
                    acc[c][dp] = fmaf(sv[dp].z, wv[2][c], acc[c][dp]);
                    acc[c][dp] = fmaf(sv[dp].w, wv[3][c], acc[c][dp]);
                }
        }
        #pragma unroll
        for (int c = 0; c < 4; ++c)
            #pragma unroll
            for (int dp = 0; dp < 8; ++dp)
                ht[(tp * 8 + dp) * 256 + tj + 64 * c] = fmaxf(acc[c][dp], 0.f);
    }
    __syncthreads();

    // GEMM2: out[p][o] = z + b2[o] + sum_jj ht[p][jj]*w2[jj][o]
    // tile: 4 p (tp2*4+dp) x 2 o (2*to2, 2*to2+1), jj in groups of 4 (float4)
    {
        int to2 = t & 31, tp2 = t >> 5;      // o-pair base, p base
        int o = 2 * to2;
        float2 a2[4];
        float2 bo = *(const float2*)(b2 + o);
        #pragma unroll
        for (int dp = 0; dp < 4; ++dp) a2[dp] = bo;
        for (int jg = 0; jg < 64; ++jg) {
            float4 hv[4];
            #pragma unroll
            for (int dp = 0; dp < 4; ++dp)
                hv[dp] = *(const float4*)(ht + (tp2 * 4 + dp) * 256 + 4 * jg);
            float2 w0 = *(const float2*)(w2 + (4 * jg + 0) * 64 + o);
            float2 w1v = *(const float2*)(w2 + (4 * jg + 1) * 64 + o);
            float2 w2v = *(const float2*)(w2 + (4 * jg + 2) * 64 + o);
            float2 w3v = *(const float2*)(w2 + (4 * jg + 3) * 64 + o);
            #pragma unroll
            for (int dp = 0; dp < 4; ++dp) {
                a2[dp].x = fmaf(hv[dp].x, w0.x, a2[dp].x);
                a2[dp].y = fmaf(hv[dp].x, w0.y, a2[dp].y);
                a2[dp].x = fmaf(hv[dp].y, w1v.x, a2[dp].x);
                a2[dp].y = fmaf(hv[dp].y, w1v.y, a2[dp].y);
                a2[dp].x = fmaf(hv[dp].z, w2v.x, a2[dp].x);
                a2[dp].y = fmaf(hv[dp].z, w2v.y, a2[dp].y);
                a2[dp].x = fmaf(hv[dp].w, w3v.x, a2[dp].x);
                a2[dp].y = fmaf(hv[dp].w, w3v.y, a2[dp].y);
            }
        }
        #pragma unroll
        for (int dp = 0; dp < 4; ++dp) {
            int p = tp2 * 4 + dp;
            size_t gi = (size_t)(p0 + p) * 64 + o;
            float2 zv = *(const float2*)(z + gi);
            float2 r;
            r.x = zv.x + a2[dp].x;
            r.y = zv.y + a2[dp].y;
            *(float2*)(out + gi) = r;
        }
    }
}

// ---------------------------------------------------------------------------
extern "C" void kernel_launch(void* const* d_in, const int* in_sizes, int n_in,
                              void* d_out, int out_size, void* d_ws, size_t ws_size,
                              hipStream_t stream) {
    const float* z   = (const float*)d_in[0];
    const float* x   = (const float*)d_in[1];
    const float* fw1 = (const float*)d_in[2];
    const float* fw2 = (const float*)d_in[3];
    const float* w1  = (const float*)d_in[4];
    const float* b1  = (const float*)d_in[5];
    const float* w2  = (const float*)d_in[6];
    const float* b2  = (const float*)d_in[7];

    // workspace: only small tables (~2.1 MB)
    float* ws   = (float*)d_ws;
    float* Tp   = ws;                    // 8192 floats
    float* fwp1 = Tp + 8192;             // 262144
    float* fwp2 = fwp1 + 262144;         // 262144
    float* s    = (float*)d_out;         // s lives in d_out (fully overwritten)

    k_setup<<<2080, 256, 0, stream>>>(fw1, fw2, Tp, fwp1, fwp2);
    k_spec<0><<<1024, 256, 0, stream>>>(x, z, fwp1, Tp, s);
    k_spec<1><<<1024, 256, 0, stream>>>(x, z, fwp2, Tp, s);
    k_ffn<<<4096, 256, 0, stream>>>(s, z, w1, b1, w2, b2, (float*)d_out);
}